// Round 4
// baseline (514.725 us; speedup 1.0000x reference)
//
#include <hip/hip_runtime.h>
#include <hip/hip_bf16.h>
#include <math.h>

// ---------- types ----------
typedef __bf16 bf16_t;
typedef __bf16 bf16x8 __attribute__((ext_vector_type(8)));
typedef __bf16 bf16x4 __attribute__((ext_vector_type(4)));
typedef float  f32x4  __attribute__((ext_vector_type(4)));

#define B_ 4
#define S_ 4096
#define D_ 1024
#define N_ 256
#define M_ (B_*S_)   // 16384

// fast activations: v_exp_f32 + v_rcp_f32 (~1 ulp each, plenty for bf16 out)
__device__ __forceinline__ float fsig(float x){
    return __builtin_amdgcn_rcpf(1.0f + __expf(-x));
}
__device__ __forceinline__ float ftanh(float x){
    return 1.0f - 2.0f*__builtin_amdgcn_rcpf(1.0f + __expf(2.0f*x));
}

// ---------- all weight transposes in one launch ----------
struct TJobs {
    const float* in[7];
    bf16_t*      out[7];
    int R[7];
    int C[7];
};

__global__ void transpose_all(TJobs j){
    int z = blockIdx.z;
    int R = j.R[z], C = j.C[z];
    int c0 = blockIdx.x*32, r0 = blockIdx.y*32;
    if (c0 >= C || r0 >= R) return;
    __shared__ float tile[32][33];
    int tx = threadIdx.x, ty = threadIdx.y;       // x:0..31, y:0..7
    const float* in = j.in[z];
    bf16_t* out = j.out[z];
    #pragma unroll
    for (int i=0;i<32;i+=8)
        tile[ty+i][tx] = in[(size_t)(r0+ty+i)*C + (c0+tx)];
    __syncthreads();
    #pragma unroll
    for (int i=0;i<32;i+=8)
        out[(size_t)(c0+ty+i)*R + (r0+tx)] = (bf16_t)tile[tx][ty+i];
}

// ---------- LayerNorm: x f32 [M][D] -> h bf16 ----------
__global__ void ln_kernel(const float* __restrict__ x, const float* __restrict__ gw,
                          const float* __restrict__ bw, bf16_t* __restrict__ h){
    int row = blockIdx.x;
    int t = threadIdx.x;                           // 256 threads, 4 elems each
    float4 v = ((const float4*)(x + (size_t)row*D_))[t];
    float s = v.x+v.y+v.z+v.w;
    float q = v.x*v.x+v.y*v.y+v.z*v.z+v.w*v.w;
    #pragma unroll
    for (int o=1;o<64;o<<=1){ s += __shfl_xor(s,o,64); q += __shfl_xor(q,o,64); }
    __shared__ float sw[4], sq[4];
    int wid = t>>6;
    if ((t&63)==0){ sw[wid]=s; sq[wid]=q; }
    __syncthreads();
    s = sw[0]+sw[1]+sw[2]+sw[3];
    q = sq[0]+sq[1]+sq[2]+sq[3];
    float mu = s*(1.0f/D_);
    float rs = rsqrtf(q*(1.0f/D_) - mu*mu + 1e-5f);
    float4 gv = ((const float4*)gw)[t];
    float4 bv = ((const float4*)bw)[t];
    bf16x4 o4;
    o4[0] = (bf16_t)((v.x-mu)*rs*gv.x + bv.x);
    o4[1] = (bf16_t)((v.y-mu)*rs*gv.y + bv.y);
    o4[2] = (bf16_t)((v.z-mu)*rs*gv.z + bv.z);
    o4[3] = (bf16_t)((v.w-mu)*rs*gv.w + bv.w);
    *(bf16x4*)(h + (size_t)row*D_ + t*4) = o4;
}

// ---------- depthwise conv1d k=3 pad=1 along S ----------
__global__ void conv_kernel(const bf16_t* __restrict__ h, const float* __restrict__ w,
                            const float* __restrict__ mb, bf16_t* __restrict__ mix){
    int idx = blockIdx.x*256 + threadIdx.x;
    int g8  = idx & 127;
    int row = idx >> 7;                            // b*S + s
    int s   = row & (S_-1);
    int d0  = g8*8;
    const bf16_t* hr = h + (size_t)row*D_ + d0;
    bf16x8 cur = *(const bf16x8*)hr;
    bf16x8 prv, nxt;
    #pragma unroll
    for (int i=0;i<8;i++){ prv[i]=(bf16_t)0.0f; nxt[i]=(bf16_t)0.0f; }
    if (s > 0)      prv = *(const bf16x8*)(hr - D_);
    if (s < S_-1)   nxt = *(const bf16x8*)(hr + D_);
    bf16x8 ov;
    #pragma unroll
    for (int i=0;i<8;i++){
        int d = d0+i;
        float o = (float)prv[i]*w[d*3] + (float)cur[i]*w[d*3+1] + (float)nxt[i]*w[d*3+2] + mb[d];
        ov[i] = (bf16_t)o;
    }
    *(bf16x8*)(mix + (size_t)row*D_ + d0) = ov;
}

// ---------- MFMA GEMM: 128x256 block tile, wave tile 64x128, BK=32, LDS dbuf ----------
// 4 waves in 2x2 grid; per wave 4x8 grid of 16x16x32 MFMAs.
// MODE 0: fused N=2816 epilogue (u | xs/dc/sel | g); every 256-col tile falls
//         entirely in one region (boundaries at 1024/1280/1536/1792 all %256==0)
// MODE 1: z = g*(acc+bso) + (1-g)*u -> bf16
// MODE 2: out = resid + acc + bout -> f32
struct Epi {
    const float *b0,*b1,*b2,*b3,*b4;
    bf16_t *u, *g, *z;
    bf16_t *xs, *dc, *sel;
    const bf16_t *gbuf, *ubuf;
    const float *resid;
    float *outp;
};

#define LDSW 48   // 96B row stride: empirically the ~128 conflict-cyc/iter floor (r1)

template<int MODE>
__global__ __launch_bounds__(256,2)
void gemm_kernel(const bf16_t* __restrict__ A, const bf16_t* __restrict__ Bt,
                 int K, Epi e){
    __shared__ bf16_t As[2][128*LDSW];   // 2 x 12KB
    __shared__ bf16_t Bs[2][256*LDSW];   // 2 x 24KB  (total 72KB)
    int tid  = threadIdx.x;
    int m0   = blockIdx.x*128;
    int n0   = blockIdx.y*256;
    int wave = tid>>6, lane = tid&63;
    int wm = (wave>>1)*64;       // 0 or 64
    int wn = (wave&1)*128;       // 0 or 128
    int lm = lane&15, quad = lane>>4;

    f32x4 acc[4][8];
    #pragma unroll
    for (int i=0;i<4;i++)
        #pragma unroll
        for (int j=0;j<8;j++)
            #pragma unroll
            for (int r=0;r<4;r++) acc[i][j][r]=0.0f;

    int ar = tid>>2;            // 0..63
    int ac = (tid&3)*8;         // 0,8,16,24
    const bf16_t* pA0 = A  + (size_t)(m0+ar    )*K + ac;
    const bf16_t* pA1 = A  + (size_t)(m0+ar+ 64)*K + ac;
    const bf16_t* pB0 = Bt + (size_t)(n0+ar    )*K + ac;
    const bf16_t* pB1 = Bt + (size_t)(n0+ar+ 64)*K + ac;
    const bf16_t* pB2 = Bt + (size_t)(n0+ar+128)*K + ac;
    const bf16_t* pB3 = Bt + (size_t)(n0+ar+192)*K + ac;
    int wa0 = (ar    )*LDSW + ac;
    int wa1 = (ar+ 64)*LDSW + ac;
    int wb2 = (ar+128)*LDSW + ac;
    int wb3 = (ar+192)*LDSW + ac;

    int aOff[4], bOff[8];
    #pragma unroll
    for (int i=0;i<4;i++) aOff[i] = (wm+i*16+lm)*LDSW + quad*8;
    #pragma unroll
    for (int j=0;j<8;j++) bOff[j] = (wn+j*16+lm)*LDSW + quad*8;

    // prologue: tile 0 -> regs -> LDS buf0; prefetch tile 1 -> regs
    bf16x8 ra0 = *(const bf16x8*)(pA0);
    bf16x8 ra1 = *(const bf16x8*)(pA1);
    bf16x8 rb0 = *(const bf16x8*)(pB0);
    bf16x8 rb1 = *(const bf16x8*)(pB1);
    bf16x8 rb2 = *(const bf16x8*)(pB2);
    bf16x8 rb3 = *(const bf16x8*)(pB3);
    *(bf16x8*)&As[0][wa0] = ra0;
    *(bf16x8*)&As[0][wa1] = ra1;
    *(bf16x8*)&Bs[0][wa0] = rb0;
    *(bf16x8*)&Bs[0][wa1] = rb1;
    *(bf16x8*)&Bs[0][wb2] = rb2;
    *(bf16x8*)&Bs[0][wb3] = rb3;
    if (K > 32){
        ra0 = *(const bf16x8*)(pA0 + 32);
        ra1 = *(const bf16x8*)(pA1 + 32);
        rb0 = *(const bf16x8*)(pB0 + 32);
        rb1 = *(const bf16x8*)(pB1 + 32);
        rb2 = *(const bf16x8*)(pB2 + 32);
        rb3 = *(const bf16x8*)(pB3 + 32);
    }

    int buf = 0;
    for (int k0=0; k0<K; k0+=32, buf^=1){
        __syncthreads();
        if (k0+32 < K){
            *(bf16x8*)&As[buf^1][wa0] = ra0;
            *(bf16x8*)&As[buf^1][wa1] = ra1;
            *(bf16x8*)&Bs[buf^1][wa0] = rb0;
            *(bf16x8*)&Bs[buf^1][wa1] = rb1;
            *(bf16x8*)&Bs[buf^1][wb2] = rb2;
            *(bf16x8*)&Bs[buf^1][wb3] = rb3;
            if (k0+64 < K){
                ra0 = *(const bf16x8*)(pA0 + k0+64);
                ra1 = *(const bf16x8*)(pA1 + k0+64);
                rb0 = *(const bf16x8*)(pB0 + k0+64);
                rb1 = *(const bf16x8*)(pB1 + k0+64);
                rb2 = *(const bf16x8*)(pB2 + k0+64);
                rb3 = *(const bf16x8*)(pB3 + k0+64);
            }
        }
        bf16x8 aF[4], bF[8];
        #pragma unroll
        for (int i=0;i<4;i++) aF[i] = *(const bf16x8*)&As[buf][aOff[i]];
        #pragma unroll
        for (int j=0;j<8;j++) bF[j] = *(const bf16x8*)&Bs[buf][bOff[j]];
        #pragma unroll
        for (int i=0;i<4;i++)
            #pragma unroll
            for (int j=0;j<8;j++)
                acc[i][j] = __builtin_amdgcn_mfma_f32_16x16x32_bf16(aF[i], bF[j], acc[i][j], 0,0,0);
    }

    // epilogue: row=(lane>>4)*4+reg, col=lane&15 within each 16x16 tile
    #pragma unroll
    for (int i=0;i<4;i++){
        #pragma unroll
        for (int j=0;j<8;j++){
            #pragma unroll
            for (int r=0;r<4;r++){
                int row = m0 + wm + i*16 + quad*4 + r;
                int col = n0 + wn + j*16 + lm;
                float v = acc[i][j][r];
                if (MODE==0){
                    if (n0 < 1024){
                        e.u[(size_t)row*D_ + col] = (bf16_t)ftanh(v + e.b0[col]);
                    } else if (n0 == 1024){
                        int cc = col & 255;
                        e.xs[(size_t)row*N_ + cc] = (bf16_t)ftanh(v + e.b1[cc]);
                    } else if (n0 == 1280){
                        int cc = col & 255;
                        e.dc[(size_t)row*N_ + cc] = (bf16_t)fsig(v + e.b2[cc]);
                    } else if (n0 == 1536){
                        int cc = col & 255;
                        e.sel[(size_t)row*N_ + cc] = (bf16_t)fsig(v + e.b3[cc]);
                    } else {
                        int cc = col - 1792;
                        e.g[(size_t)row*D_ + cc] = (bf16_t)fsig(v + e.b4[cc]);
                    }
                } else if (MODE==1){
                    float yv = v + e.b0[col];
                    float gv = (float)e.gbuf[(size_t)row*D_ + col];
                    float uv = (float)e.ubuf[(size_t)row*D_ + col];
                    e.z[(size_t)row*D_ + col] = (bf16_t)(gv*yv + (1.0f-gv)*uv);
                } else {
                    e.outp[(size_t)row*D_ + col] = e.resid[(size_t)row*D_ + col] + v + e.b0[col];
                }
            }
        }
    }
}

// ---------- chunked affine scan: state = d*state + (1-d)*x (bf16 in, bf16 out) ----------
__global__ void scan_p1(const bf16_t* __restrict__ dc, const bf16_t* __restrict__ xs,
                        float* __restrict__ aggA, float* __restrict__ aggB){
    int bc = blockIdx.x;            // b*64 + chunk
    int b = bc>>6, ch = bc&63;
    int n = threadIdx.x;
    size_t base = ((size_t)b*S_ + ch*64)*N_ + n;
    float A = 1.0f, Bc = 0.0f;
    for (int t=0;t<64;t++){
        float d = (float)dc[base + (size_t)t*N_];
        float x = (float)xs[base + (size_t)t*N_];
        A  = d*A;
        Bc = d*Bc + (1.0f-d)*x;
    }
    aggA[(size_t)bc*N_+n]=A; aggB[(size_t)bc*N_+n]=Bc;
}

__global__ void scan_p2(const float* __restrict__ aggA, const float* __restrict__ aggB,
                        float* __restrict__ pre){
    int b = blockIdx.x, n = threadIdx.x;
    float s = 0.0f;
    for (int ch=0; ch<64; ch++){
        size_t i = ((size_t)b*64+ch)*N_+n;
        pre[i] = s;
        s = aggA[i]*s + aggB[i];
    }
}

__global__ void scan_p3(const bf16_t* __restrict__ dc, const bf16_t* __restrict__ xs,
                        const bf16_t* __restrict__ sel, const float* __restrict__ pre,
                        bf16_t* __restrict__ ss){
    int bc = blockIdx.x;
    int b = bc>>6, ch = bc&63;
    int n = threadIdx.x;
    size_t base = ((size_t)b*S_ + ch*64)*N_ + n;
    float s = pre[(size_t)bc*N_+n];
    for (int t=0;t<64;t++){
        size_t i = base + (size_t)t*N_;
        float d = (float)dc[i], x = (float)xs[i];
        s = d*s + (1.0f-d)*x;
        ss[i] = (bf16_t)((float)sel[i]*s);
    }
}

// ---------- launch ----------
extern "C" void kernel_launch(void* const* d_in, const int* in_sizes, int n_in,
                              void* d_out, int out_size, void* d_ws, size_t ws_size,
                              hipStream_t stream){
    const float* x    = (const float*)d_in[0];
    const float* ln_g = (const float*)d_in[1];
    const float* ln_b = (const float*)d_in[2];
    const float* mixw = (const float*)d_in[3];
    const float* mixb = (const float*)d_in[4];
    const float* Wi   = (const float*)d_in[5];
    const float* bi   = (const float*)d_in[6];
    const float* Wsin = (const float*)d_in[7];
    const float* bsin = (const float*)d_in[8];
    const float* Wd   = (const float*)d_in[9];
    const float* bd   = (const float*)d_in[10];
    const float* Wsel = (const float*)d_in[11];
    const float* bsel = (const float*)d_in[12];
    const float* Wso  = (const float*)d_in[13];
    const float* bso  = (const float*)d_in[14];
    const float* Wg   = (const float*)d_in[15];
    const float* bg   = (const float*)d_in[16];
    const float* Wout = (const float*)d_in[17];
    const float* bout = (const float*)d_in[18];
    float* out = (float*)d_out;

    char* p = (char*)d_ws;
    auto alloc = [&](size_t bytes)->char*{ char* r=p; p += (bytes+255)&~(size_t)255; return r; };
    bf16_t* hB    = (bf16_t*)alloc((size_t)M_*D_*2);
    bf16_t* mixB  = (bf16_t*)alloc((size_t)M_*D_*2);
    bf16_t* uB    = (bf16_t*)alloc((size_t)M_*D_*2);
    bf16_t* gB    = (bf16_t*)alloc((size_t)M_*D_*2);
    bf16_t* ssB   = (bf16_t*)alloc((size_t)M_*N_*2);
    bf16_t* xs    = (bf16_t*)alloc((size_t)M_*N_*2);
    bf16_t* dc    = (bf16_t*)alloc((size_t)M_*N_*2);
    bf16_t* sel   = (bf16_t*)alloc((size_t)M_*N_*2);
    bf16_t* WbigT = (bf16_t*)alloc((size_t)2816*1024*2);  // [Wi|Wsin|Wd|Wsel|Wg] cols as rows
    bf16_t* WsoT  = (bf16_t*)alloc(1024*256*2);
    bf16_t* WoutT = (bf16_t*)alloc(1024*1024*2);
    float*  aggA  = (float*)alloc((size_t)4*64*256*4);
    float*  aggB  = (float*)alloc((size_t)4*64*256*4);
    float*  pre   = (float*)alloc((size_t)4*64*256*4);
    bf16_t* zB = mixB;   // alias: mixB dead after big GEMM; z written after scan

    // one launch for all 7 weight transposes (f32 [R][C] -> bf16 [C][R])
    TJobs tj;
    tj.in[0]=Wi;   tj.out[0]=WbigT;            tj.R[0]=1024; tj.C[0]=1024;
    tj.in[1]=Wsin; tj.out[1]=WbigT+1024*1024;  tj.R[1]=1024; tj.C[1]=256;
    tj.in[2]=Wd;   tj.out[2]=WbigT+1280*1024;  tj.R[2]=1024; tj.C[2]=256;
    tj.in[3]=Wsel; tj.out[3]=WbigT+1536*1024;  tj.R[3]=1024; tj.C[3]=256;
    tj.in[4]=Wg;   tj.out[4]=WbigT+(size_t)1792*1024; tj.R[4]=1024; tj.C[4]=1024;
    tj.in[5]=Wso;  tj.out[5]=WsoT;             tj.R[5]=256;  tj.C[5]=1024;
    tj.in[6]=Wout; tj.out[6]=WoutT;            tj.R[6]=1024; tj.C[6]=1024;
    transpose_all<<<dim3(32,32,7), dim3(32,8), 0, stream>>>(tj);

    ln_kernel  <<<M_, 256, 0, stream>>>(x, ln_g, ln_b, hB);
    conv_kernel<<<M_*128/256, 256, 0, stream>>>(hB, mixw, mixb, mixB);

    // fused: u | xs/dc/sel | g = act(mixed @ [Wi|Wsin|Wd|Wsel|Wg] + b)
    Epi e0 = {};
    e0.b0=bi; e0.b1=bsin; e0.b2=bd; e0.b3=bsel; e0.b4=bg;
    e0.u=uB; e0.g=gB; e0.xs=xs; e0.dc=dc; e0.sel=sel;
    gemm_kernel<0><<<dim3(M_/128, 11), 256, 0, stream>>>(mixB, WbigT, 1024, e0);

    scan_p1<<<4*64, 256, 0, stream>>>(dc, xs, aggA, aggB);
    scan_p2<<<4,    256, 0, stream>>>(aggA, aggB, pre);
    scan_p3<<<4*64, 256, 0, stream>>>(dc, xs, sel, pre, ssB);

    // z = g*(ss@Wso+bso) + (1-g)*u
    Epi e1 = {};
    e1.b0=bso; e1.gbuf=gB; e1.ubuf=uB; e1.z=zB;
    gemm_kernel<1><<<dim3(M_/128, 4), 256, 0, stream>>>(ssB, WsoT, 256, e1);

    // out = x + z@Wout + bout
    Epi e2 = {};
    e2.b0=bout; e2.resid=x; e2.outp=out;
    gemm_kernel<2><<<dim3(M_/128, 4), 256, 0, stream>>>(zB, WoutT, 1024, e2);
}

// Round 5
// 404.084 us; speedup vs baseline: 1.2738x; 1.2738x over previous
//
#include <hip/hip_runtime.h>
#include <hip/hip_bf16.h>
#include <math.h>

// ---------- types ----------
typedef __bf16 bf16_t;
typedef __bf16 bf16x8 __attribute__((ext_vector_type(8)));
typedef __bf16 bf16x4 __attribute__((ext_vector_type(4)));
typedef float  f32x4  __attribute__((ext_vector_type(4)));

#define B_ 4
#define S_ 4096
#define D_ 1024
#define N_ 256
#define M_ (B_*S_)   // 16384

// fast activations: v_exp_f32 + v_rcp_f32 (~1 ulp each, plenty for bf16 out)
__device__ __forceinline__ float fsig(float x){
    return __builtin_amdgcn_rcpf(1.0f + __expf(-x));
}
__device__ __forceinline__ float ftanh(float x){
    return 1.0f - 2.0f*__builtin_amdgcn_rcpf(1.0f + __expf(2.0f*x));
}

// ---------- all weight transposes in one launch ----------
struct TJobs {
    const float* in[7];
    bf16_t*      out[7];
    int R[7];
    int C[7];
};

__global__ void transpose_all(TJobs j){
    int z = blockIdx.z;
    int R = j.R[z], C = j.C[z];
    int c0 = blockIdx.x*32, r0 = blockIdx.y*32;
    if (c0 >= C || r0 >= R) return;
    __shared__ float tile[32][33];
    int tx = threadIdx.x, ty = threadIdx.y;       // x:0..31, y:0..7
    const float* in = j.in[z];
    bf16_t* out = j.out[z];
    #pragma unroll
    for (int i=0;i<32;i+=8)
        tile[ty+i][tx] = in[(size_t)(r0+ty+i)*C + (c0+tx)];
    __syncthreads();
    #pragma unroll
    for (int i=0;i<32;i+=8)
        out[(size_t)(c0+ty+i)*R + (r0+tx)] = (bf16_t)tile[tx][ty+i];
}

// ---------- LayerNorm: x f32 [M][D] -> h bf16 ----------
__global__ void ln_kernel(const float* __restrict__ x, const float* __restrict__ gw,
                          const float* __restrict__ bw, bf16_t* __restrict__ h){
    int row = blockIdx.x;
    int t = threadIdx.x;                           // 256 threads, 4 elems each
    float4 v = ((const float4*)(x + (size_t)row*D_))[t];
    float s = v.x+v.y+v.z+v.w;
    float q = v.x*v.x+v.y*v.y+v.z*v.z+v.w*v.w;
    #pragma unroll
    for (int o=1;o<64;o<<=1){ s += __shfl_xor(s,o,64); q += __shfl_xor(q,o,64); }
    __shared__ float sw[4], sq[4];
    int wid = t>>6;
    if ((t&63)==0){ sw[wid]=s; sq[wid]=q; }
    __syncthreads();
    s = sw[0]+sw[1]+sw[2]+sw[3];
    q = sq[0]+sq[1]+sq[2]+sq[3];
    float mu = s*(1.0f/D_);
    float rs = rsqrtf(q*(1.0f/D_) - mu*mu + 1e-5f);
    float4 gv = ((const float4*)gw)[t];
    float4 bv = ((const float4*)bw)[t];
    bf16x4 o4;
    o4[0] = (bf16_t)((v.x-mu)*rs*gv.x + bv.x);
    o4[1] = (bf16_t)((v.y-mu)*rs*gv.y + bv.y);
    o4[2] = (bf16_t)((v.z-mu)*rs*gv.z + bv.z);
    o4[3] = (bf16_t)((v.w-mu)*rs*gv.w + bv.w);
    *(bf16x4*)(h + (size_t)row*D_ + t*4) = o4;
}

// ---------- depthwise conv1d k=3 pad=1 along S ----------
__global__ void conv_kernel(const bf16_t* __restrict__ h, const float* __restrict__ w,
                            const float* __restrict__ mb, bf16_t* __restrict__ mix){
    int idx = blockIdx.x*256 + threadIdx.x;
    int g8  = idx & 127;
    int row = idx >> 7;                            // b*S + s
    int s   = row & (S_-1);
    int d0  = g8*8;
    const bf16_t* hr = h + (size_t)row*D_ + d0;
    bf16x8 cur = *(const bf16x8*)hr;
    bf16x8 prv, nxt;
    #pragma unroll
    for (int i=0;i<8;i++){ prv[i]=(bf16_t)0.0f; nxt[i]=(bf16_t)0.0f; }
    if (s > 0)      prv = *(const bf16x8*)(hr - D_);
    if (s < S_-1)   nxt = *(const bf16x8*)(hr + D_);
    bf16x8 ov;
    #pragma unroll
    for (int i=0;i<8;i++){
        int d = d0+i;
        float o = (float)prv[i]*w[d*3] + (float)cur[i]*w[d*3+1] + (float)nxt[i]*w[d*3+2] + mb[d];
        ov[i] = (bf16_t)o;
    }
    *(bf16x8*)(mix + (size_t)row*D_ + d0) = ov;
}

// ---------- MFMA GEMM: 128x128 tile, BK=32, VGPR-staged + LDS dbuf (r3 core) ----------
// Epilogue retiles acc through LDS for fully-coalesced global I/O.
// MODE 0: fused N=2816 epilogue (u | xs/dc/sel | g); 128-col tile is in one region
// MODE 1: z = g*(acc+bso) + (1-g)*u -> bf16
// MODE 2: out = resid + acc + bout -> f32
struct Epi {
    const float *b0,*b1,*b2,*b3,*b4;
    bf16_t *u, *g, *z;
    bf16_t *xs, *dc, *sel;
    const bf16_t *gbuf, *ubuf;
    const float *resid;
    float *outp;
};

#define LDSW 40   // 80B row stride: <=2-way bank aliasing on b128 reads/writes

template<int MODE>
__global__ __launch_bounds__(256,3)
void gemm_kernel(const bf16_t* __restrict__ A, const bf16_t* __restrict__ Bt,
                 int K, Epi e){
    __shared__ __align__(16) char smem[40960];
    bf16_t* As = (bf16_t*)smem;            // [2][128*LDSW]  20KB
    bf16_t* Bs = (bf16_t*)(smem + 20480);  // [2][128*LDSW]  20KB
    const int BUF = 128*LDSW;
    int tid  = threadIdx.x;
    int m0   = blockIdx.x*128;
    int n0   = blockIdx.y*128;
    int wave = tid>>6, lane = tid&63;
    int wm = (wave>>1)*64, wn = (wave&1)*64;
    int lm = lane&15, quad = lane>>4;

    f32x4 acc[4][4];
    #pragma unroll
    for (int i=0;i<4;i++)
        #pragma unroll
        for (int j=0;j<4;j++)
            #pragma unroll
            for (int r=0;r<4;r++) acc[i][j][r]=0.0f;

    int ar = tid>>2;            // 0..63
    int ac = (tid&3)*8;         // 0,8,16,24
    const bf16_t* pA0 = A  + (size_t)(m0+ar   )*K + ac;
    const bf16_t* pA1 = A  + (size_t)(m0+ar+64)*K + ac;
    const bf16_t* pB0 = Bt + (size_t)(n0+ar   )*K + ac;
    const bf16_t* pB1 = Bt + (size_t)(n0+ar+64)*K + ac;
    int w0 = (ar   )*LDSW + ac;
    int w1 = (ar+64)*LDSW + ac;

    int aOff[4], bOff[4];
    #pragma unroll
    for (int i=0;i<4;i++){
        aOff[i] = (wm+i*16+lm)*LDSW + quad*8;
        bOff[i] = (wn+i*16+lm)*LDSW + quad*8;
    }

    // prologue: tile 0 -> regs -> LDS buf0; prefetch tile 1 -> regs
    bf16x8 ra0 = *(const bf16x8*)(pA0);
    bf16x8 ra1 = *(const bf16x8*)(pA1);
    bf16x8 rb0 = *(const bf16x8*)(pB0);
    bf16x8 rb1 = *(const bf16x8*)(pB1);
    *(bf16x8*)&As[w0] = ra0;
    *(bf16x8*)&As[w1] = ra1;
    *(bf16x8*)&Bs[w0] = rb0;
    *(bf16x8*)&Bs[w1] = rb1;
    if (K > 32){
        ra0 = *(const bf16x8*)(pA0 + 32);
        ra1 = *(const bf16x8*)(pA1 + 32);
        rb0 = *(const bf16x8*)(pB0 + 32);
        rb1 = *(const bf16x8*)(pB1 + 32);
    }

    int buf = 0;
    for (int k0=0; k0<K; k0+=32, buf^=1){
        __syncthreads();
        int nb = (buf^1)*BUF;
        if (k0+32 < K){
            *(bf16x8*)&As[nb+w0] = ra0;
            *(bf16x8*)&As[nb+w1] = ra1;
            *(bf16x8*)&Bs[nb+w0] = rb0;
            *(bf16x8*)&Bs[nb+w1] = rb1;
            if (k0+64 < K){
                ra0 = *(const bf16x8*)(pA0 + k0+64);
                ra1 = *(const bf16x8*)(pA1 + k0+64);
                rb0 = *(const bf16x8*)(pB0 + k0+64);
                rb1 = *(const bf16x8*)(pB1 + k0+64);
            }
        }
        int cb = buf*BUF;
        bf16x8 aF[4], bF[4];
        #pragma unroll
        for (int i=0;i<4;i++){
            aF[i] = *(const bf16x8*)&As[cb+aOff[i]];
            bF[i] = *(const bf16x8*)&Bs[cb+bOff[i]];
        }
        #pragma unroll
        for (int i=0;i<4;i++)
            #pragma unroll
            for (int j=0;j<4;j++)
                acc[i][j] = __builtin_amdgcn_mfma_f32_16x16x32_bf16(aF[i], bF[j], acc[i][j], 0,0,0);
    }

    // ---- epilogue: retile through LDS for coalesced global I/O ----
    // acc layout: row = wm+i*16+quad*4+r, col = wn+j*16+lm (within 128x128 tile)
    if (MODE==2){
        // f32 path, two 64-col phases; LDS tile stride 68 f32
        float* T = (float*)smem;
        #pragma unroll
        for (int p=0;p<2;p++){
            __syncthreads();
            if (wn == p*64){
                #pragma unroll
                for (int i=0;i<4;i++)
                    #pragma unroll
                    for (int j=0;j<4;j++)
                        #pragma unroll
                        for (int r=0;r<4;r++)
                            T[(wm+i*16+quad*4+r)*68 + j*16+lm] = acc[i][j][r];
            }
            __syncthreads();
            int c4 = tid&15;             // float4 chunk 0..15 (64 cols)
            int gcol = n0 + p*64 + c4*4;
            float4 bias = *(const float4*)&e.b0[gcol];
            #pragma unroll
            for (int it=0; it<8; it++){
                int rr = (tid>>4) + it*16;
                f32x4 v = *(const f32x4*)&T[rr*68 + c4*4];
                size_t gi = (size_t)(m0+rr)*D_ + gcol;
                float4 res = *(const float4*)&e.resid[gi];
                float4 o;
                o.x = v[0]+res.x+bias.x; o.y = v[1]+res.y+bias.y;
                o.z = v[2]+res.z+bias.z; o.w = v[3]+res.w+bias.w;
                *(float4*)&e.outp[gi] = o;
            }
        }
    } else {
        // bf16 path: one 128x128 bf16 tile, stride 136
        bf16_t* Tb = (bf16_t*)smem;
        __syncthreads();
        if (MODE==0){
            const float* bp; int cbase; bool ut = (n0 < 1280);
            if (n0 < 1024){ bp=e.b0; cbase=n0; }
            else if (n0 < 1792){
                int sub=(n0-1024)>>8;
                bp = sub==0? e.b1 : sub==1? e.b2 : e.b3;
                cbase = (n0-1024)&255;
            } else { bp=e.b4; cbase=n0-1792; }
            #pragma unroll
            for (int i=0;i<4;i++)
                #pragma unroll
                for (int j=0;j<4;j++){
                    float bv = bp[cbase + wn+j*16+lm];
                    #pragma unroll
                    for (int r=0;r<4;r++){
                        float v = acc[i][j][r] + bv;
                        v = ut ? ftanh(v) : fsig(v);
                        Tb[(wm+i*16+quad*4+r)*136 + wn+j*16+lm] = (bf16_t)v;
                    }
                }
        } else { // MODE 1: store y = acc + bso (combine with g,u in read phase)
            #pragma unroll
            for (int i=0;i<4;i++)
                #pragma unroll
                for (int j=0;j<4;j++){
                    float bv = e.b0[n0 + wn+j*16+lm];
                    #pragma unroll
                    for (int r=0;r<4;r++)
                        Tb[(wm+i*16+quad*4+r)*136 + wn+j*16+lm] = (bf16_t)(acc[i][j][r] + bv);
                }
        }
        __syncthreads();
        // read phase: 16 chunks of 8 bf16 across 128 cols; rows tid>>4 + it*16
        int ch = tid&15;
        if (MODE==0){
            bf16_t* dst; int width, colbase;
            if (n0 < 1024){ dst=e.u; width=D_; colbase=n0; }
            else if (n0 < 1792){
                int sub=(n0-1024)>>8;
                dst = sub==0? e.xs : sub==1? e.dc : e.sel;
                width=N_; colbase=(n0-1024)&255;
            } else { dst=e.g; width=D_; colbase=n0-1792; }
            #pragma unroll
            for (int it=0; it<8; it++){
                int rr = (tid>>4) + it*16;
                bf16x8 v = *(const bf16x8*)&Tb[rr*136 + ch*8];
                *(bf16x8*)&dst[(size_t)(m0+rr)*width + colbase + ch*8] = v;
            }
        } else {
            #pragma unroll
            for (int it=0; it<8; it++){
                int rr = (tid>>4) + it*16;
                bf16x8 y = *(const bf16x8*)&Tb[rr*136 + ch*8];
                size_t gi = (size_t)(m0+rr)*D_ + n0 + ch*8;
                bf16x8 gv = *(const bf16x8*)&e.gbuf[gi];
                bf16x8 uv = *(const bf16x8*)&e.ubuf[gi];
                bf16x8 o;
                #pragma unroll
                for (int q=0;q<8;q++){
                    float gf = (float)gv[q];
                    o[q] = (bf16_t)(gf*(float)y[q] + (1.0f-gf)*(float)uv[q]);
                }
                *(bf16x8*)&e.z[gi] = o;
            }
        }
    }
}

// ---------- chunked affine scan: state = d*state + (1-d)*x (bf16 in, bf16 out) ----------
__global__ void scan_p1(const bf16_t* __restrict__ dc, const bf16_t* __restrict__ xs,
                        float* __restrict__ aggA, float* __restrict__ aggB){
    int bc = blockIdx.x;            // b*64 + chunk
    int b = bc>>6, ch = bc&63;
    int n = threadIdx.x;
    size_t base = ((size_t)b*S_ + ch*64)*N_ + n;
    float A = 1.0f, Bc = 0.0f;
    for (int t=0;t<64;t++){
        float d = (float)dc[base + (size_t)t*N_];
        float x = (float)xs[base + (size_t)t*N_];
        A  = d*A;
        Bc = d*Bc + (1.0f-d)*x;
    }
    aggA[(size_t)bc*N_+n]=A; aggB[(size_t)bc*N_+n]=Bc;
}

__global__ void scan_p2(const float* __restrict__ aggA, const float* __restrict__ aggB,
                        float* __restrict__ pre){
    int b = blockIdx.x, n = threadIdx.x;
    float s = 0.0f;
    for (int ch=0; ch<64; ch++){
        size_t i = ((size_t)b*64+ch)*N_+n;
        pre[i] = s;
        s = aggA[i]*s + aggB[i];
    }
}

__global__ void scan_p3(const bf16_t* __restrict__ dc, const bf16_t* __restrict__ xs,
                        const bf16_t* __restrict__ sel, const float* __restrict__ pre,
                        bf16_t* __restrict__ ss){
    int bc = blockIdx.x;
    int b = bc>>6, ch = bc&63;
    int n = threadIdx.x;
    size_t base = ((size_t)b*S_ + ch*64)*N_ + n;
    float s = pre[(size_t)bc*N_+n];
    for (int t=0;t<64;t++){
        size_t i = base + (size_t)t*N_;
        float d = (float)dc[i], x = (float)xs[i];
        s = d*s + (1.0f-d)*x;
        ss[i] = (bf16_t)((float)sel[i]*s);
    }
}

// ---------- launch ----------
extern "C" void kernel_launch(void* const* d_in, const int* in_sizes, int n_in,
                              void* d_out, int out_size, void* d_ws, size_t ws_size,
                              hipStream_t stream){
    const float* x    = (const float*)d_in[0];
    const float* ln_g = (const float*)d_in[1];
    const float* ln_b = (const float*)d_in[2];
    const float* mixw = (const float*)d_in[3];
    const float* mixb = (const float*)d_in[4];
    const float* Wi   = (const float*)d_in[5];
    const float* bi   = (const float*)d_in[6];
    const float* Wsin = (const float*)d_in[7];
    const float* bsin = (const float*)d_in[8];
    const float* Wd   = (const float*)d_in[9];
    const float* bd   = (const float*)d_in[10];
    const float* Wsel = (const float*)d_in[11];
    const float* bsel = (const float*)d_in[12];
    const float* Wso  = (const float*)d_in[13];
    const float* bso  = (const float*)d_in[14];
    const float* Wg   = (const float*)d_in[15];
    const float* bg   = (const float*)d_in[16];
    const float* Wout = (const float*)d_in[17];
    const float* bout = (const float*)d_in[18];
    float* out = (float*)d_out;

    char* p = (char*)d_ws;
    auto alloc = [&](size_t bytes)->char*{ char* r=p; p += (bytes+255)&~(size_t)255; return r; };
    bf16_t* hB    = (bf16_t*)alloc((size_t)M_*D_*2);
    bf16_t* mixB  = (bf16_t*)alloc((size_t)M_*D_*2);
    bf16_t* uB    = (bf16_t*)alloc((size_t)M_*D_*2);
    bf16_t* gB    = (bf16_t*)alloc((size_t)M_*D_*2);
    bf16_t* ssB   = (bf16_t*)alloc((size_t)M_*N_*2);
    bf16_t* xs    = (bf16_t*)alloc((size_t)M_*N_*2);
    bf16_t* dc    = (bf16_t*)alloc((size_t)M_*N_*2);
    bf16_t* sel   = (bf16_t*)alloc((size_t)M_*N_*2);
    bf16_t* WbigT = (bf16_t*)alloc((size_t)2816*1024*2);  // [Wi|Wsin|Wd|Wsel|Wg] cols as rows
    bf16_t* WsoT  = (bf16_t*)alloc(1024*256*2);
    bf16_t* WoutT = (bf16_t*)alloc(1024*1024*2);
    float*  aggA  = (float*)alloc((size_t)4*64*256*4);
    float*  aggB  = (float*)alloc((size_t)4*64*256*4);
    float*  pre   = (float*)alloc((size_t)4*64*256*4);
    bf16_t* zB = mixB;   // alias: mixB dead after big GEMM; z written after scan

    // one launch for all 7 weight transposes (f32 [R][C] -> bf16 [C][R])
    TJobs tj;
    tj.in[0]=Wi;   tj.out[0]=WbigT;            tj.R[0]=1024; tj.C[0]=1024;
    tj.in[1]=Wsin; tj.out[1]=WbigT+1024*1024;  tj.R[1]=1024; tj.C[1]=256;
    tj.in[2]=Wd;   tj.out[2]=WbigT+1280*1024;  tj.R[2]=1024; tj.C[2]=256;
    tj.in[3]=Wsel; tj.out[3]=WbigT+1536*1024;  tj.R[3]=1024; tj.C[3]=256;
    tj.in[4]=Wg;   tj.out[4]=WbigT+(size_t)1792*1024; tj.R[4]=1024; tj.C[4]=1024;
    tj.in[5]=Wso;  tj.out[5]=WsoT;             tj.R[5]=256;  tj.C[5]=1024;
    tj.in[6]=Wout; tj.out[6]=WoutT;            tj.R[6]=1024; tj.C[6]=1024;
    transpose_all<<<dim3(32,32,7), dim3(32,8), 0, stream>>>(tj);

    ln_kernel  <<<M_, 256, 0, stream>>>(x, ln_g, ln_b, hB);
    conv_kernel<<<M_*128/256, 256, 0, stream>>>(hB, mixw, mixb, mixB);

    // fused: u | xs/dc/sel | g = act(mixed @ [Wi|Wsin|Wd|Wsel|Wg] + b)
    Epi e0 = {};
    e0.b0=bi; e0.b1=bsin; e0.b2=bd; e0.b3=bsel; e0.b4=bg;
    e0.u=uB; e0.g=gB; e0.xs=xs; e0.dc=dc; e0.sel=sel;
    gemm_kernel<0><<<dim3(M_/128, 22), 256, 0, stream>>>(mixB, WbigT, 1024, e0);

    scan_p1<<<4*64, 256, 0, stream>>>(dc, xs, aggA, aggB);
    scan_p2<<<4,    256, 0, stream>>>(aggA, aggB, pre);
    scan_p3<<<4*64, 256, 0, stream>>>(dc, xs, sel, pre, ssB);

    // z = g*(ss@Wso+bso) + (1-g)*u
    Epi e1 = {};
    e1.b0=bso; e1.gbuf=gB; e1.ubuf=uB; e1.z=zB;
    gemm_kernel<1><<<dim3(M_/128, 8), 256, 0, stream>>>(ssB, WsoT, 256, e1);

    // out = x + z@Wout + bout
    Epi e2 = {};
    e2.b0=bout; e2.resid=x; e2.outp=out;
    gemm_kernel<2><<<dim3(M_/128, 8), 256, 0, stream>>>(zB, WoutT, 1024, e2);
}